// Round 2
// baseline (1029.589 us; speedup 1.0000x reference)
//
#include <hip/hip_runtime.h>
#include <cstdint>

// NonLocalBlock MI355X implementation (fp16 MFMA everywhere, fp32 accum).
// Pipeline:
//   k_init: weights->fp16 (Wv|Wq|Wk concat, Wu), zero rowmax/rowsum/BN stats
//   k_xt:   x [b][c][n] f32 -> xt [b][n][c] fp16 (LDS 64x64 transpose)
//   k_proj: [768,512]x[512,4096] per b -> v [b][o][n], q/k [b][n][i]
//   k_attn0: S=QK^T/dist, per-row global atomicMax (monotone-encoded u32)
//   k_attn1: P=exp(S-rowmax) fp16 (unnormalized) + rowsum atomicAdd (per chunk)
//   k_pv:   y[n][o] = (P @ V^T) / rowsum                              (per chunk)
//   k_u:    u = Wu @ y^T -> [b][c][n] fp16 + fused BN partial sum/sumsq
//   k_bnfin, k_out: BN finalize; relu(u*sc+sh+x) f32
// Workspace: adaptive P-chunking; 113.5/145/210 MB depending on ws_size.

typedef unsigned short u16;
typedef unsigned int u32;
using half8 = __attribute__((ext_vector_type(8))) _Float16;
using f32x4 = __attribute__((ext_vector_type(4))) float;

#define B_ 8
#define N_ 4096
#define C_ 512
#define I_ 128

__device__ __forceinline__ u16 f2h(float f) {
  return __builtin_bit_cast(u16, (_Float16)f);
}
__device__ __forceinline__ float h2f(u16 v) {
  return (float)__builtin_bit_cast(_Float16, v);
}

__device__ __forceinline__ void gld16(const void* g, void* l) {
  __builtin_amdgcn_global_load_lds((const __attribute__((address_space(1))) u32*)g,
                                   (__attribute__((address_space(3))) u32*)l, 16, 0, 0);
}

__device__ __forceinline__ f32x4 mfma16(half8 a, half8 b, f32x4 c) {
  return __builtin_amdgcn_mfma_f32_16x16x32_f16(a, b, c, 0, 0, 0);
}

// ---------------- common 128x128 BT-GEMM core (BK=32, 256 threads, 4 waves) ---
// A [128 rows][K], B [128 rows][K] row-major fp16 (rows of B = output cols).
// LDS chunk XOR-swizzle: chunk ^= (r&3)^((r>>2)&3)  -> ~2-way bank conflicts.
__device__ __forceinline__ void gemm128_bt(const u16* __restrict__ Ap, int lda,
                                           const u16* __restrict__ Bp, int ldb,
                                           int K, u16* As, u16* Bs,
                                           f32x4 (&acc)[4][4])
{
  const int tid = threadIdx.x;
  const int w = tid >> 6, l = tid & 63;
  const int wr = w >> 1, wc = w & 1;
  const int srow = tid >> 2, schunk = tid & 3;

  for (int k0 = 0; k0 < K; k0 += 32) {
    __syncthreads();                       // previous-iter LDS reads done
#pragma unroll
    for (int i = 0; i < 2; ++i) {
      int r = i * 64 + srow;               // 0..127
      int sc = (schunk ^ (r & 3) ^ ((r >> 2) & 3)) << 3;
      gld16(Ap + (size_t)r * lda + k0 + sc, As + i * 2048 + w * 512);
      gld16(Bp + (size_t)r * ldb + k0 + sc, Bs + i * 2048 + w * 512);
    }
    __syncthreads();                       // staging visible (vmcnt drained)

    half8 af[4], bf[4];
#pragma unroll
    for (int mi = 0; mi < 4; ++mi) {
      int rl = wr * 64 + mi * 16 + (l & 15);
      int ch = (l >> 4) ^ (rl & 3) ^ ((rl >> 2) & 3);
      af[mi] = *(const half8*)(As + rl * 32 + ch * 8);
    }
#pragma unroll
    for (int nj = 0; nj < 4; ++nj) {
      int rl = wc * 64 + nj * 16 + (l & 15);
      int ch = (l >> 4) ^ (rl & 3) ^ ((rl >> 2) & 3);
      bf[nj] = *(const half8*)(Bs + rl * 32 + ch * 8);
    }
#pragma unroll
    for (int mi = 0; mi < 4; ++mi)
#pragma unroll
      for (int nj = 0; nj < 4; ++nj)
        acc[mi][nj] = mfma16(af[mi], bf[nj], acc[mi][nj]);
  }
}

// ---------------- init ---------------------------------------------------------
__global__ __launch_bounds__(256) void k_init(const float* __restrict__ Wv,
    const float* __restrict__ Wq, const float* __restrict__ Wk,
    const float* __restrict__ Wu, u16* __restrict__ wqkv, u16* __restrict__ wu,
    u32* __restrict__ rowmaxI, float* __restrict__ rowsum, float* __restrict__ stats)
{
  int i = blockIdx.x * 256 + threadIdx.x;
  if (i < 768 * 512) {
    int r = i >> 9, c = i & 511;
    float val = (r < 512) ? Wv[i] : (r < 640 ? Wq[(r - 512) * 512 + c]
                                             : Wk[(r - 640) * 512 + c]);
    wqkv[i] = f2h(val);
  }
  if (i < 512 * 512) wu[i] = f2h(Wu[i]);
  if (i < B_ * N_) { rowmaxI[i] = 0u; rowsum[i] = 0.f; }   // 0 < any real enc()
  if (i < 1024) stats[i] = 0.f;
}

// ---------------- x transpose+convert: [b][c][n] f32 -> [b][n][c] fp16 --------
__global__ __launch_bounds__(256) void k_xt(const float* __restrict__ x,
                                            u16* __restrict__ xt)
{
  __shared__ float t[64][65];
  int id = blockIdx.x;                     // 8b * 8cg * 64ng = 4096
  int b = id >> 9, cg = (id >> 6) & 7, ng = id & 63;
  int c0 = cg * 64, n0 = ng * 64;
  int tid = threadIdx.x;
  const float* xs = x + ((size_t)b * C_ + c0) * N_ + n0;
#pragma unroll
  for (int p = 0; p < 16; ++p) {
    int idx = p * 256 + tid; int r = idx >> 6, cl = idx & 63;
    t[r][cl] = xs[(size_t)r * N_ + cl];
  }
  __syncthreads();
  u16* xd = xt + ((size_t)b * N_ + n0) * C_ + c0;
#pragma unroll
  for (int p = 0; p < 16; ++p) {
    int idx = p * 256 + tid; int r = idx >> 6, cl = idx & 63;
    xd[(size_t)r * C_ + cl] = f2h(t[cl][r]);
  }
}

// ---------------- fused QKV projection ---------------------------------------
__global__ __launch_bounds__(256) void k_proj(const u16* __restrict__ wqkv,
    const u16* __restrict__ xt, u16* __restrict__ v, u16* __restrict__ q,
    u16* __restrict__ kk)
{
  __shared__ u16 As[128 * 32], Bs[128 * 32];
  int id = blockIdx.x;                     // 6 * 32 * 8
  int bm = id % 6; int rest = id / 6; int bn = rest & 31; int b = rest >> 5;
  const u16* Ap = wqkv + bm * 128 * 512;
  const u16* Bp = xt + ((size_t)b * N_ + bn * 128) * C_;
  f32x4 acc[4][4];
#pragma unroll
  for (int a1 = 0; a1 < 4; ++a1)
#pragma unroll
    for (int a2 = 0; a2 < 4; ++a2) acc[a1][a2] = f32x4{0.f, 0.f, 0.f, 0.f};
  gemm128_bt(Ap, 512, Bp, 512, 512, As, Bs, acc);

  int tid = threadIdx.x, w = tid >> 6, l = tid & 63, wr = w >> 1, wc = w & 1;
#pragma unroll
  for (int mi = 0; mi < 4; ++mi)
#pragma unroll
    for (int nj = 0; nj < 4; ++nj)
#pragma unroll
      for (int e = 0; e < 4; ++e) {
        int gr = bm * 128 + wr * 64 + mi * 16 + ((l >> 4) << 2) + e;
        int gc = bn * 128 + wc * 64 + nj * 16 + (l & 15);
        u16 bv = f2h(acc[mi][nj][e]);
        if (bm < 4)       v[((size_t)b * C_ + gr) * N_ + gc] = bv;
        else if (bm == 4) q[((size_t)b * N_ + gc) * I_ + (gr - 512)] = bv;
        else              kk[((size_t)b * N_ + gc) * I_ + (gr - 640)] = bv;
      }
}

// ---------------- shared QK^T tile core (K=128) -------------------------------
__device__ __forceinline__ void stage128(const u16* __restrict__ src, u16* Ts,
                                         int tid, int w)
{
  int rr = tid >> 4, sch = tid & 15;
#pragma unroll
  for (int i = 0; i < 8; ++i) {
    int r = i * 16 + rr;
    int sc = (sch ^ (r & 15)) << 3;
    gld16(src + (size_t)r * I_ + sc, Ts + i * 2048 + w * 512);
  }
}

__device__ __forceinline__ void qk_tile(const u16* __restrict__ qp,
    const u16* __restrict__ kp, u16* Ts, f32x4 (&acc)[4][4])
{
  int tid = threadIdx.x, w = tid >> 6, l = tid & 63, wr = w >> 1, wc = w & 1;
  stage128(qp, Ts, tid, w);
  __syncthreads();
  half8 qf[4][4];
#pragma unroll
  for (int mi = 0; mi < 4; ++mi)
#pragma unroll
    for (int kc = 0; kc < 4; ++kc) {
      int rl = wr * 64 + mi * 16 + (l & 15);
      int ch = (kc * 4 + (l >> 4)) ^ (rl & 15);
      qf[mi][kc] = *(const half8*)(Ts + rl * 128 + ch * 8);
    }
  __syncthreads();                         // Q reads done before overwrite
  stage128(kp, Ts, tid, w);
  __syncthreads();

#pragma unroll
  for (int a1 = 0; a1 < 4; ++a1)
#pragma unroll
    for (int a2 = 0; a2 < 4; ++a2) acc[a1][a2] = f32x4{0.f, 0.f, 0.f, 0.f};
#pragma unroll
  for (int kc = 0; kc < 4; ++kc) {
    half8 bfr[4];
#pragma unroll
    for (int nj = 0; nj < 4; ++nj) {
      int rl = wc * 64 + nj * 16 + (l & 15);
      int ch = (kc * 4 + (l >> 4)) ^ (rl & 15);
      bfr[nj] = *(const half8*)(Ts + rl * 128 + ch * 8);
    }
#pragma unroll
    for (int mi = 0; mi < 4; ++mi)
#pragma unroll
      for (int nj = 0; nj < 4; ++nj)
        acc[mi][nj] = mfma16(qf[mi][kc], bfr[nj], acc[mi][nj]);
  }
}

// ---------------- attention phase 0: rowmax ----------------------------------
__global__ __launch_bounds__(256) void k_attn0(const u16* __restrict__ q,
    const u16* __restrict__ kk, u32* __restrict__ rowmaxI)
{
  __shared__ u16 Ts[128 * 128];
  int id = blockIdx.x;                     // 32 nt * 32 mt
  int nt = id & 31, mt = id >> 5;
  int tid = threadIdx.x, w = tid >> 6, l = tid & 63, wr = w >> 1, wc = w & 1;

  float rd[4][4][4];
#pragma unroll
  for (int mi = 0; mi < 4; ++mi)
#pragma unroll
    for (int e = 0; e < 4; ++e) {
      int gn = nt * 128 + wr * 64 + mi * 16 + ((l >> 4) << 2) + e;
      float inf_ = (float)(gn >> 6), jnf = (float)(gn & 63);
#pragma unroll
      for (int nj = 0; nj < 4; ++nj) {
        int gm = mt * 128 + wc * 64 + nj * 16 + (l & 15);
        float dx = inf_ - (float)(gm >> 6), dy = jnf - (float)(gm & 63);
        rd[mi][nj][e] = 1.0f / (sqrtf(dx * dx + dy * dy) + 1.0f);
      }
    }

#pragma unroll 1
  for (int b = 0; b < 8; ++b) {
    const u16* qp = q  + (size_t)b * N_ * I_ + (size_t)nt * 128 * I_;
    const u16* kp = kk + (size_t)b * N_ * I_ + (size_t)mt * 128 * I_;
    __syncthreads();                       // prev-b LDS reads done
    f32x4 acc[4][4];
    qk_tile(qp, kp, Ts, acc);
#pragma unroll
    for (int mi = 0; mi < 4; ++mi)
#pragma unroll
      for (int e = 0; e < 4; ++e) {
        float m = -3e38f;
#pragma unroll
        for (int nj = 0; nj < 4; ++nj)
          m = fmaxf(m, acc[mi][nj][e] * rd[mi][nj][e]);
#pragma unroll
        for (int d = 1; d < 16; d <<= 1) m = fmaxf(m, __shfl_xor(m, d, 64));
        if ((l & 15) == 0) {
          int gn = nt * 128 + wr * 64 + mi * 16 + ((l >> 4) << 2) + e;
          u32 u = __builtin_bit_cast(u32, m);
          u = (u & 0x80000000u) ? ~u : (u | 0x80000000u);     // monotone encode
          atomicMax(rowmaxI + b * N_ + gn, u);
        }
      }
  }
}

// ---------------- attention phase 1: P + rowsum (chunked) ---------------------
__global__ __launch_bounds__(256) void k_attn1(const u16* __restrict__ q,
    const u16* __restrict__ kk, const u32* __restrict__ rowmaxI,
    float* __restrict__ rowsum, u16* __restrict__ P, int ntOff, int c)
{
  __shared__ u16 Ts[128 * 128];
  int id = blockIdx.x;                     // c * 32 * 8
  int ntl = id % c, mt = (id / c) & 31, b = id / (c * 32);
  int nt = ntOff + ntl;
  int tid = threadIdx.x, w = tid >> 6, l = tid & 63, wr = w >> 1, wc = w & 1;

  float rd[4][4][4];
#pragma unroll
  for (int mi = 0; mi < 4; ++mi)
#pragma unroll
    for (int e = 0; e < 4; ++e) {
      int gn = nt * 128 + wr * 64 + mi * 16 + ((l >> 4) << 2) + e;
      float inf_ = (float)(gn >> 6), jnf = (float)(gn & 63);
#pragma unroll
      for (int nj = 0; nj < 4; ++nj) {
        int gm = mt * 128 + wc * 64 + nj * 16 + (l & 15);
        float dx = inf_ - (float)(gm >> 6), dy = jnf - (float)(gm & 63);
        rd[mi][nj][e] = 1.0f / (sqrtf(dx * dx + dy * dy) + 1.0f);
      }
    }

  const u16* qp = q  + (size_t)b * N_ * I_ + (size_t)nt * 128 * I_;
  const u16* kp = kk + (size_t)b * N_ * I_ + (size_t)mt * 128 * I_;
  f32x4 acc[4][4];
  qk_tile(qp, kp, Ts, acc);

#pragma unroll
  for (int mi = 0; mi < 4; ++mi)
#pragma unroll
    for (int e = 0; e < 4; ++e) {
      int lrow = wr * 64 + mi * 16 + ((l >> 4) << 2) + e;
      int gn = nt * 128 + lrow;
      int nloc = ntl * 128 + lrow;
      u32 u = rowmaxI[b * N_ + gn];
      float rm = __builtin_bit_cast(float,
                   (u & 0x80000000u) ? (u & 0x7fffffffu) : ~u);
      float ps = 0.f;
#pragma unroll
      for (int nj = 0; nj < 4; ++nj) {
        float p = __expf(acc[mi][nj][e] * rd[mi][nj][e] - rm);
        ps += p;
        int gm = mt * 128 + wc * 64 + nj * 16 + (l & 15);
        P[((size_t)b * (c * 128) + nloc) * N_ + gm] = f2h(p);
      }
#pragma unroll
      for (int d = 1; d < 16; d <<= 1) ps += __shfl_xor(ps, d, 64);
      if ((l & 15) == 0) atomicAdd(rowsum + b * N_ + gn, ps);
    }
}

// ---------------- PV GEMM: y[n][o] = (P @ V^T) / rowsum -----------------------
__global__ __launch_bounds__(256) void k_pv(const u16* __restrict__ P,
    const u16* __restrict__ v, const float* __restrict__ rowsum,
    u16* __restrict__ y, int ntOff, int c)
{
  __shared__ u16 As[128 * 32], Bs[128 * 32];
  int id = blockIdx.x;                     // c * 4 * 8
  int bmL = id % c, bn = (id / c) & 3, b = id / (c * 4);
  const u16* Ap = P + ((size_t)b * (c * 128) + (size_t)bmL * 128) * N_;
  const u16* Bp = v + (size_t)b * C_ * N_ + (size_t)bn * 128 * N_;
  f32x4 acc[4][4];
#pragma unroll
  for (int a1 = 0; a1 < 4; ++a1)
#pragma unroll
    for (int a2 = 0; a2 < 4; ++a2) acc[a1][a2] = f32x4{0.f, 0.f, 0.f, 0.f};
  gemm128_bt(Ap, N_, Bp, N_, N_, As, Bs, acc);

  int tid = threadIdx.x, w = tid >> 6, l = tid & 63, wr = w >> 1, wc = w & 1;
#pragma unroll
  for (int mi = 0; mi < 4; ++mi)
#pragma unroll
    for (int e = 0; e < 4; ++e) {
      int gn = (ntOff + bmL) * 128 + wr * 64 + mi * 16 + ((l >> 4) << 2) + e;
      float li = 1.0f / rowsum[b * N_ + gn];
#pragma unroll
      for (int nj = 0; nj < 4; ++nj) {
        int go = bn * 128 + wc * 64 + nj * 16 + (l & 15);
        y[((size_t)b * N_ + gn) * C_ + go] = f2h(acc[mi][nj][e] * li);
      }
    }
}

// ---------------- u = Wu @ y^T, + BN partial stats ----------------------------
__global__ __launch_bounds__(256) void k_u(const u16* __restrict__ wu,
    const u16* __restrict__ y, u16* __restrict__ uo, float* __restrict__ stats)
{
  __shared__ u16 As[128 * 32], Bs[128 * 32];
  int id = blockIdx.x;                     // 4 * 32 * 8
  int bm = id & 3, bn = (id >> 2) & 31, b = id >> 7;
  const u16* Ap = wu + bm * 128 * 512;
  const u16* Bp = y + (size_t)b * N_ * C_ + (size_t)bn * 128 * C_;
  f32x4 acc[4][4];
#pragma unroll
  for (int a1 = 0; a1 < 4; ++a1)
#pragma unroll
    for (int a2 = 0; a2 < 4; ++a2) acc[a1][a2] = f32x4{0.f, 0.f, 0.f, 0.f};
  gemm128_bt(Ap, 512, Bp, 512, 512, As, Bs, acc);

  int tid = threadIdx.x, w = tid >> 6, l = tid & 63, wr = w >> 1, wc = w & 1;
#pragma unroll
  for (int mi = 0; mi < 4; ++mi)
#pragma unroll
    for (int e = 0; e < 4; ++e) {
      int gr = bm * 128 + wr * 64 + mi * 16 + ((l >> 4) << 2) + e;  // channel
      float s = 0.f, s2 = 0.f;
#pragma unroll
      for (int nj = 0; nj < 4; ++nj) {
        float val = acc[mi][nj][e];
        int gc = bn * 128 + wc * 64 + nj * 16 + (l & 15);
        uo[((size_t)b * C_ + gr) * N_ + gc] = f2h(val);
        s += val; s2 += val * val;
      }
#pragma unroll
      for (int d = 1; d < 16; d <<= 1) {
        s  += __shfl_xor(s, d, 64);
        s2 += __shfl_xor(s2, d, 64);
      }
      if ((l & 15) == 0) {
        atomicAdd(stats + gr, s);
        atomicAdd(stats + 512 + gr, s2);
      }
    }
}

// ---------------- BN finalize -------------------------------------------------
__global__ __launch_bounds__(256) void k_bnfin(const float* __restrict__ stats,
    const float* __restrict__ gamma, const float* __restrict__ beta,
    float* __restrict__ coef)
{
  int c = blockIdx.x * 256 + threadIdx.x;
  if (c < 512) {
    const float inv = 1.0f / (float)(B_ * N_);
    float mean = stats[c] * inv;
    float var = stats[512 + c] * inv - mean * mean;
    float sc = gamma[c] * rsqrtf(var + 1e-5f);
    coef[c] = sc;
    coef[512 + c] = beta[c] - mean * sc;
  }
}

// ---------------- epilogue: relu(u_bn + x) ------------------------------------
__global__ __launch_bounds__(256) void k_out(const u16* __restrict__ uo,
    const float* __restrict__ x, const float* __restrict__ coef,
    float* __restrict__ out)
{
  int t = blockIdx.x * 256 + threadIdx.x;  // 2,097,152 threads, 8 elems each
  size_t base = (size_t)t * 8;
  int c = (t >> 9) & 511;
  float sc = coef[c], sh = coef[512 + c];
  using short8 = __attribute__((ext_vector_type(8))) short;
  short8 uv = *(const short8*)(uo + base);
  const float4* xp = (const float4*)(x + base);
  float4 x0 = xp[0], x1 = xp[1];
  float4 o0, o1;
  o0.x = fmaxf(h2f((u16)uv[0]) * sc + sh + x0.x, 0.f);
  o0.y = fmaxf(h2f((u16)uv[1]) * sc + sh + x0.y, 0.f);
  o0.z = fmaxf(h2f((u16)uv[2]) * sc + sh + x0.z, 0.f);
  o0.w = fmaxf(h2f((u16)uv[3]) * sc + sh + x0.w, 0.f);
  o1.x = fmaxf(h2f((u16)uv[4]) * sc + sh + x1.x, 0.f);
  o1.y = fmaxf(h2f((u16)uv[5]) * sc + sh + x1.y, 0.f);
  o1.z = fmaxf(h2f((u16)uv[6]) * sc + sh + x1.z, 0.f);
  o1.w = fmaxf(h2f((u16)uv[7]) * sc + sh + x1.w, 0.f);
  float4* op = (float4*)(out + base);
  op[0] = o0; op[1] = o1;
}

// ---------------- launcher ----------------------------------------------------
extern "C" void kernel_launch(void* const* d_in, const int* in_sizes, int n_in,
                              void* d_out, int out_size, void* d_ws, size_t ws_size,
                              hipStream_t stream)
{
  const float* x  = (const float*)d_in[0];
  const float* Wv = (const float*)d_in[1];
  const float* Wq = (const float*)d_in[2];
  const float* Wk = (const float*)d_in[3];
  const float* Wu = (const float*)d_in[4];
  const float* gm = (const float*)d_in[5];
  const float* bt = (const float*)d_in[6];

  char* ws = (char*)d_ws;
  // region map (y aliases xt; uo aliases P):
  u16* xt       = (u16*)(ws + 0);            // 33,554,432  (xt, then y)
  u16* y        = xt;
  u16* v        = (u16*)(ws + 33554432);     // 33,554,432
  u16* q        = (u16*)(ws + 67108864);     //  8,388,608
  u16* kk       = (u16*)(ws + 75497472);     //  8,388,608
  u16* wqkv     = (u16*)(ws + 83886080);     //    786,432
  u16* wu       = (u16*)(ws + 84672512);     //    524,288
  u32* rowmaxI  = (u32*)(ws + 85196800);     //    131,072
  float* rowsum = (float*)(ws + 85327872);   //    131,072
  float* stats  = (float*)(ws + 85458944);   //      4,096
  float* coef   = (float*)(ws + 85463040);   //      4,096
  u16* P        = (u16*)(ws + 85467136);     //  c*8,388,608 (P, then uo)
  u16* uo       = P;

  const size_t baseB = 85467136ull;
  int c = 4;                                  // P-chunk in 128-row tiles
  if      (ws_size >= baseB + 16ull * 8388608ull) c = 16;  // total ~210 MB
  else if (ws_size >= baseB +  8ull * 8388608ull) c = 8;   // total ~145 MB
  // c=4 -> total ~113.5 MB

  k_init<<<1536, 256, 0, stream>>>(Wv, Wq, Wk, Wu, wqkv, wu, rowmaxI, rowsum, stats);
  k_xt<<<4096, 256, 0, stream>>>(x, xt);
  k_proj<<<1536, 256, 0, stream>>>(wqkv, xt, v, q, kk);
  k_attn0<<<1024, 256, 0, stream>>>(q, kk, rowmaxI);
  for (int off = 0; off < 32; off += c) {
    k_attn1<<<c * 32 * 8, 256, 0, stream>>>(q, kk, rowmaxI, rowsum, P, off, c);
    k_pv<<<c * 4 * 8, 256, 0, stream>>>(P, v, rowsum, y, off, c);
  }
  k_u<<<1024, 256, 0, stream>>>(wu, y, uo, stats);
  k_bnfin<<<2, 256, 0, stream>>>(stats, gm, bt, coef);
  k_out<<<8192, 256, 0, stream>>>(uo, x, coef, (float*)d_out);
}